// Round 4
// baseline (627.083 us; speedup 1.0000x reference)
//
#include <hip/hip_runtime.h>

typedef __attribute__((ext_vector_type(8))) short bf16x8;
typedef __attribute__((ext_vector_type(4))) float f32x4;
typedef unsigned short u16;
typedef unsigned int u32;

// ---------- constants ----------
#define NWIN 2048
#define P 64
#define C 256
#define MSEL 1536
#define KEEP 48
#define REAL 40
#define H 8
#define DH 32
#define MROWS (MSEL * REAL)          // 61440 rows in the compacted activation matrix

// ws layout (u16 element offsets)
#define OFF_WQKVT  0                  // [768][256]
#define OFF_PROJT  196608             // [256][256]
#define OFF_W1T    262144             // [1024][256]
#define OFF_W2T    524288             // [256][1024]
#define OFF_A      786432             // [61440][256] bf16  (LN2 rows)
#define OFF_QKV    16515072           // [61440][768] bf16
#define OFF_ATTNO  63700992           // [61440][256] bf16

__device__ __forceinline__ u16 f2bf(float f) {
    u32 u = __float_as_uint(f);
    u += 0x7FFF + ((u >> 16) & 1);   // RNE
    return (u16)(u >> 16);
}
__device__ __forceinline__ float bf2f(u16 h) { return __uint_as_float(((u32)h) << 16); }

// ---------- weight prep: fp32 [K][N] -> bf16 [N][K] ----------
__global__ __launch_bounds__(256) void prep_weights(const float* __restrict__ qkv_w,
                                                    const float* __restrict__ proj_w,
                                                    const float* __restrict__ w1,
                                                    const float* __restrict__ w2,
                                                    u16* __restrict__ ws) {
    int i = blockIdx.x * 256 + threadIdx.x;   // 786432 total
    float v; int o;
    if (i < 196608) {
        int n = i >> 8, k = i & 255; v = qkv_w[k * 768 + n]; o = OFF_WQKVT + i;
    } else if (i < 262144) {
        int j = i - 196608; int n = j >> 8, k = j & 255; v = proj_w[k * 256 + n]; o = i;
    } else if (i < 524288) {
        int j = i - 262144; int n = j >> 8, k = j & 255; v = w1[k * 1024 + n]; o = i;
    } else {
        int j = i - 524288; int n = j >> 10, k = j & 1023; v = w2[k * 256 + n]; o = i;
    }
    ws[o] = f2bf(v);
}

// ---------- LN1 over all (N*P, C) rows -> d_out fp32 ----------
__global__ __launch_bounds__(256) void ln1_kernel(const float* __restrict__ x,
                                                  const float* __restrict__ g,
                                                  const float* __restrict__ b,
                                                  float* __restrict__ out) {
    int row = blockIdx.x * 4 + (threadIdx.x >> 6);
    int l = threadIdx.x & 63;
    const float4 v = *(const float4*)(x + (size_t)row * C + l * 4);
    float s = v.x + v.y + v.z + v.w;
    float q = v.x * v.x + v.y * v.y + v.z * v.z + v.w * v.w;
    #pragma unroll
    for (int m = 1; m < 64; m <<= 1) { s += __shfl_xor(s, m); q += __shfl_xor(q, m); }
    float mu = s * (1.0f / C);
    float var = q * (1.0f / C) - mu * mu;
    float rs = rsqrtf(var + 1e-5f);
    float4 gg = *(const float4*)(g + l * 4);
    float4 bb = *(const float4*)(b + l * 4);
    float4 o;
    o.x = (v.x - mu) * rs * gg.x + bb.x;
    o.y = (v.y - mu) * rs * gg.y + bb.y;
    o.z = (v.z - mu) * rs * gg.z + bb.z;
    o.w = (v.w - mu) * rs * gg.w + bb.w;
    *(float4*)(out + (size_t)row * C + l * 4) = o;
}

// ---------- LN2 on real rows of selected windows -> A bf16 ----------
__global__ __launch_bounds__(256) void ln2_kernel(const float* __restrict__ ln1,
                                                  const float* __restrict__ g,
                                                  const float* __restrict__ b,
                                                  const int* __restrict__ asy,
                                                  const int* __restrict__ iwin,
                                                  u16* __restrict__ A) {
    int r = blockIdx.x * 4 + (threadIdx.x >> 6);
    int l = threadIdx.x & 63;
    int flat = asy[r];
    int m = flat >> 6, p = flat & 63;
    int w = iwin[m];
    const float4 v = *(const float4*)(ln1 + ((size_t)w * P + p) * C + l * 4);
    float s = v.x + v.y + v.z + v.w;
    float q = v.x * v.x + v.y * v.y + v.z * v.z + v.w * v.w;
    #pragma unroll
    for (int mm = 1; mm < 64; mm <<= 1) { s += __shfl_xor(s, mm); q += __shfl_xor(q, mm); }
    float mu = s * (1.0f / C);
    float var = q * (1.0f / C) - mu * mu;
    float rs = rsqrtf(var + 1e-5f);
    float4 gg = *(const float4*)(g + l * 4);
    float4 bb = *(const float4*)(b + l * 4);
    ushort4 o;
    o.x = f2bf((v.x - mu) * rs * gg.x + bb.x);
    o.y = f2bf((v.y - mu) * rs * gg.y + bb.y);
    o.z = f2bf((v.z - mu) * rs * gg.z + bb.z);
    o.w = f2bf((v.w - mu) * rs * gg.w + bb.w);
    *(ushort4*)(A + (size_t)r * C + l * 4) = o;
}

// ---------- 128x128-tile bf16 MFMA GEMM, m97 structure (QKV only) ----------
template <int N, int K, class Epi>
__global__ __launch_bounds__(256) void gemm_bt(const u16* __restrict__ A,
                                               const u16* __restrict__ B, Epi epi,
                                               int chunk) {
    constexpr int NB = N / 128;
    int bid = blockIdx.x;
    bid = (bid & 7) * chunk + (bid >> 3);          // XCD-aware swizzle (grid % 8 == 0)
    int bm = bid / NB, bn = bid % NB;
    __shared__ u16 lA[128 * 64], lB[128 * 64];
    int t = threadIdx.x;
    int l = t & 63, w = t >> 6;
    int wr = w >> 1, wc = w & 1;
    int l15 = l & 15, g4 = l >> 4;
    int xr = l15 & 7;

    f32x4 acc[4][4];
    #pragma unroll
    for (int a = 0; a < 4; a++)
        #pragma unroll
        for (int bb = 0; bb < 4; bb++)
            #pragma unroll
            for (int i = 0; i < 4; i++) acc[a][bb][i] = 0.0f;

    int rbase = w * 32 + (l >> 3);
    int cg = (l & 7) ^ (l >> 3);
    const u16* gA = A + (size_t)(bm * 128 + rbase) * K + cg * 8;
    const u16* gB = B + (size_t)(bn * 128 + rbase) * K + cg * 8;

    for (int k0 = 0; k0 < K; k0 += 64) {
        __syncthreads();
        #pragma unroll
        for (int j = 0; j < 4; j++)
            __builtin_amdgcn_global_load_lds(
                (const __attribute__((address_space(1))) u32*)(gA + (size_t)j * 8 * K + k0),
                (__attribute__((address_space(3))) u32*)(lA + w * 2048 + j * 512), 16, 0, 0);
        #pragma unroll
        for (int j = 0; j < 4; j++)
            __builtin_amdgcn_global_load_lds(
                (const __attribute__((address_space(1))) u32*)(gB + (size_t)j * 8 * K + k0),
                (__attribute__((address_space(3))) u32*)(lB + w * 2048 + j * 512), 16, 0, 0);
        __syncthreads();
        #pragma unroll
        for (int kk = 0; kk < 2; kk++) {
            bf16x8 af[4], bfr[4];
            #pragma unroll
            for (int mt = 0; mt < 4; mt++)
                af[mt] = *(const bf16x8*)(lA + (wr * 64 + mt * 16 + l15) * 64
                                             + ((kk * 4 + g4) ^ xr) * 8);
            #pragma unroll
            for (int nt = 0; nt < 4; nt++)
                bfr[nt] = *(const bf16x8*)(lB + (wc * 64 + nt * 16 + l15) * 64
                                              + ((kk * 4 + g4) ^ xr) * 8);
            #pragma unroll
            for (int mt = 0; mt < 4; mt++)
                #pragma unroll
                for (int nt = 0; nt < 4; nt++)
                    acc[mt][nt] = __builtin_amdgcn_mfma_f32_16x16x32_bf16(af[mt], bfr[nt], acc[mt][nt], 0, 0, 0);
        }
    }
    int orow = bm * 128 + wr * 64, ocol = bn * 128 + wc * 64;
    #pragma unroll
    for (int mt = 0; mt < 4; mt++)
        #pragma unroll
        for (int nt = 0; nt < 4; nt++)
            #pragma unroll
            for (int rg = 0; rg < 4; rg++)
                epi(orow + mt * 16 + g4 * 4 + rg, ocol + nt * 16 + l15, acc[mt][nt][rg]);
}

struct EpiQKV {
    const float* bias; u16* out;
    __device__ void operator()(int r, int c, float v) const {
        out[(size_t)r * 768 + c] = f2bf(v + bias[c]);
    }
};

// ---------- fused per-window attention ----------
__global__ __launch_bounds__(256) void attn_kernel(const u16* __restrict__ QKV,
                                                   u16* __restrict__ out) {
    __shared__ u16 lds[4 * (48 * 80 + 32 * 80)];
    int m = blockIdx.x;
    int t = threadIdx.x, l = t & 63, w = t >> 6;
    int l15 = l & 15, g4 = l >> 4;
    u16* Pb = lds + w * (48 * 80 + 32 * 80);
    u16* Vt = Pb + 48 * 80;

    u32* z = (u32*)Pb;
    for (int i = l; i < (48 * 80 + 32 * 80) / 2; i += 64) z[i] = 0;

    const float scale = 0.17677669529663687f; // 32^-0.5

    for (int hh = 0; hh < 2; hh++) {
        int h = w + hh * 4;
        const u16* base = QKV + (size_t)m * REAL * 768 + h * 96;

        for (int i = l; i < REAL * 4; i += 64) {
            int kk = i >> 2, dg = i & 3;
            bf16x8 vv = *(const bf16x8*)(base + (size_t)kk * 768 + 64 + dg * 8);
            #pragma unroll
            for (int j = 0; j < 8; j++) Vt[(dg * 8 + j) * 80 + kk] = vv[j];
        }

        bf16x8 zf;
        #pragma unroll
        for (int i = 0; i < 8; i++) zf[i] = 0;
        bf16x8 qf[3], kf[3];
        #pragma unroll
        for (int mt = 0; mt < 3; mt++) {
            int q = mt * 16 + l15;
            qf[mt] = (q < REAL) ? *(const bf16x8*)(base + (size_t)q * 768 + g4 * 8) : zf;
        }
        #pragma unroll
        for (int nt = 0; nt < 3; nt++) {
            int kk = nt * 16 + l15;
            kf[nt] = (kk < REAL) ? *(const bf16x8*)(base + (size_t)kk * 768 + 32 + g4 * 8) : zf;
        }
        f32x4 s[3][3];
        #pragma unroll
        for (int a = 0; a < 3; a++)
            #pragma unroll
            for (int bb = 0; bb < 3; bb++)
                #pragma unroll
                for (int i = 0; i < 4; i++) s[a][bb][i] = 0.0f;
        #pragma unroll
        for (int mt = 0; mt < 3; mt++)
            #pragma unroll
            for (int nt = 0; nt < 3; nt++)
                s[mt][nt] = __builtin_amdgcn_mfma_f32_16x16x32_bf16(qf[mt], kf[nt], s[mt][nt], 0, 0, 0);

        #pragma unroll
        for (int mt = 0; mt < 3; mt++) {
            #pragma unroll
            for (int rg = 0; rg < 4; rg++) {
                float v0 = s[mt][0][rg] * scale;
                float v1 = s[mt][1][rg] * scale;
                float v2 = s[mt][2][rg] * scale;
                bool k2ok = (32 + l15) < REAL;
                float mx = fmaxf(fmaxf(v0, v1), k2ok ? v2 : -1e30f);
                #pragma unroll
                for (int xm = 1; xm < 16; xm <<= 1) mx = fmaxf(mx, __shfl_xor(mx, xm));
                float e0 = __expf(v0 - mx);
                float e1 = __expf(v1 - mx);
                float e2 = k2ok ? __expf(v2 - mx) : 0.0f;
                float sm = e0 + e1 + e2;
                #pragma unroll
                for (int xm = 1; xm < 16; xm <<= 1) sm += __shfl_xor(sm, xm);
                float inv = 1.0f / sm;
                int q = mt * 16 + g4 * 4 + rg;
                Pb[q * 80 + l15]      = f2bf(e0 * inv);
                Pb[q * 80 + 16 + l15] = f2bf(e1 * inv);
                Pb[q * 80 + 32 + l15] = f2bf(e2 * inv);
            }
        }

        f32x4 o[3][2];
        #pragma unroll
        for (int a = 0; a < 3; a++)
            #pragma unroll
            for (int bb = 0; bb < 2; bb++)
                #pragma unroll
                for (int i = 0; i < 4; i++) o[a][bb][i] = 0.0f;
        #pragma unroll
        for (int kt = 0; kt < 2; kt++) {
            bf16x8 pf[3], vf[2];
            #pragma unroll
            for (int mt = 0; mt < 3; mt++)
                pf[mt] = *(const bf16x8*)(Pb + (mt * 16 + l15) * 80 + kt * 32 + g4 * 8);
            #pragma unroll
            for (int nt = 0; nt < 2; nt++)
                vf[nt] = *(const bf16x8*)(Vt + (nt * 16 + l15) * 80 + kt * 32 + g4 * 8);
            #pragma unroll
            for (int mt = 0; mt < 3; mt++)
                #pragma unroll
                for (int nt = 0; nt < 2; nt++)
                    o[mt][nt] = __builtin_amdgcn_mfma_f32_16x16x32_bf16(pf[mt], vf[nt], o[mt][nt], 0, 0, 0);
        }
        #pragma unroll
        for (int mt = 0; mt < 3; mt++)
            #pragma unroll
            for (int nt = 0; nt < 2; nt++)
                #pragma unroll
                for (int rg = 0; rg < 4; rg++) {
                    int q = mt * 16 + g4 * 4 + rg;
                    if (q < REAL)
                        out[((size_t)m * REAL + q) * C + h * DH + nt * 16 + l15] = f2bf(o[mt][nt][rg]);
                }
    }
}

// ---------- fused tail: proj + residual(ls1) + MLP1 + GELU(tanh) + MLP2 + residual(ls2) + scatter ----------
// One block = 64 rows, 4 waves (wave w owns a 64-col output slice; weights read once/block).
// Xs[64][256] / Hs[64][128]: power-of-2 strides, XOR-swizzled 16B groups (grp ^= row&7) ->
// conflict-free ds_read_b128. Xs staged via global_load_lds with pre-swizzled source.
__global__ __launch_bounds__(256) void fused_tail(const u16* __restrict__ AttnO,
                                                  const u16* __restrict__ Abuf,
                                                  const u16* __restrict__ ProjT,
                                                  const u16* __restrict__ W1T,
                                                  const u16* __restrict__ W2T,
                                                  const float* __restrict__ proj_b,
                                                  const float* __restrict__ ls1,
                                                  const float* __restrict__ b1,
                                                  const float* __restrict__ b2,
                                                  const float* __restrict__ ls2,
                                                  const int* __restrict__ asy,
                                                  const int* __restrict__ iwin,
                                                  float* __restrict__ out) {
    __shared__ u16 Xs[64 * 256];
    __shared__ u16 Hs[64 * 128];
    int r0 = blockIdx.x * 64;
    int t = threadIdx.x, l = t & 63, w = t >> 6;
    int l15 = l & 15, g4 = l >> 4;
    int xr = l15 & 7;

    // phase 0: stage AttnO strip -> Xs (global_load_lds, source pre-swizzled)
    {
        int rr = w * 16 + (l >> 5);
        int cg0 = l & 31;
        #pragma unroll
        for (int j = 0; j < 8; j++) {
            int row = rr + j * 2;
            int sg = cg0 ^ (row & 7);
            __builtin_amdgcn_global_load_lds(
                (const __attribute__((address_space(1))) u32*)(AttnO + (size_t)(r0 + row) * 256 + sg * 8),
                (__attribute__((address_space(3))) u32*)(Xs + w * 4096 + j * 512), 16, 0, 0);
        }
    }
    __syncthreads();

    // phase 1: proj. wave w: rows 0..64 x cols [w*64, w*64+64)
    f32x4 accp[4][4];
    #pragma unroll
    for (int a = 0; a < 4; a++)
        #pragma unroll
        for (int bb = 0; bb < 4; bb++)
            #pragma unroll
            for (int i = 0; i < 4; i++) accp[a][bb][i] = 0.0f;
    for (int k0 = 0; k0 < 256; k0 += 32) {
        bf16x8 af[4], bf[4];
        #pragma unroll
        for (int mt = 0; mt < 4; mt++)
            af[mt] = *(const bf16x8*)(Xs + (mt * 16 + l15) * 256 + (((k0 >> 3) + g4) ^ xr) * 8);
        #pragma unroll
        for (int nt = 0; nt < 4; nt++)
            bf[nt] = *(const bf16x8*)(ProjT + (size_t)(w * 64 + nt * 16 + l15) * 256 + k0 + g4 * 8);
        #pragma unroll
        for (int mt = 0; mt < 4; mt++)
            #pragma unroll
            for (int nt = 0; nt < 4; nt++)
                accp[mt][nt] = __builtin_amdgcn_mfma_f32_16x16x32_bf16(af[mt], bf[nt], accp[mt][nt], 0, 0, 0);
    }
    __syncthreads();   // all proj reads of Xs done before overwrite

    // phase 2a: Xs = (proj + b)*ls1   (swizzled scalar writes)
    #pragma unroll
    for (int nt = 0; nt < 4; nt++) {
        int col = w * 64 + nt * 16 + l15;
        float pb = proj_b[col], l1 = ls1[col];
        int cg = col >> 3, ci = col & 7;
        #pragma unroll
        for (int mt = 0; mt < 4; mt++)
            #pragma unroll
            for (int rg = 0; rg < 4; rg++) {
                int row = mt * 16 + g4 * 4 + rg;
                Xs[row * 256 + (cg ^ (row & 7)) * 8 + ci] = f2bf((accp[mt][nt][rg] + pb) * l1);
            }
    }
    __syncthreads();

    // phase 2b: Xs += Abuf (vectorized 16B merge)
    #pragma unroll
    for (int i = 0; i < 8; i++) {
        int row = i * 8 + (t >> 5);
        int cg = t & 31;
        bf16x8 a = *(const bf16x8*)(Abuf + (size_t)(r0 + row) * 256 + cg * 8);
        u16* px = Xs + row * 256 + (cg ^ (row & 7)) * 8;
        bf16x8 xv = *(bf16x8*)px;
        #pragma unroll
        for (int j = 0; j < 8; j++)
            xv[j] = (short)f2bf(bf2f((u16)a[j]) + bf2f((u16)xv[j]));
        *(bf16x8*)px = xv;
    }
    __syncthreads();

    // phase 3: MLP over 8 chunks of 128 H-cols
    f32x4 acco[4][4];
    #pragma unroll
    for (int a = 0; a < 4; a++)
        #pragma unroll
        for (int bb = 0; bb < 4; bb++)
            #pragma unroll
            for (int i = 0; i < 4; i++) acco[a][bb][i] = 0.0f;

    for (int kc = 0; kc < 8; kc++) {
        // 3a: Hc = Xs @ W1slice (wave w: H-cols [w*32, w*32+32) of the chunk)
        f32x4 acch[4][2];
        #pragma unroll
        for (int a = 0; a < 4; a++)
            #pragma unroll
            for (int bb = 0; bb < 2; bb++)
                #pragma unroll
                for (int i = 0; i < 4; i++) acch[a][bb][i] = 0.0f;
        for (int k0 = 0; k0 < 256; k0 += 32) {
            bf16x8 af[4], bf[2];
            #pragma unroll
            for (int mt = 0; mt < 4; mt++)
                af[mt] = *(const bf16x8*)(Xs + (mt * 16 + l15) * 256 + (((k0 >> 3) + g4) ^ xr) * 8);
            #pragma unroll
            for (int nt = 0; nt < 2; nt++)
                bf[nt] = *(const bf16x8*)(W1T + (size_t)(kc * 128 + w * 32 + nt * 16 + l15) * 256 + k0 + g4 * 8);
            #pragma unroll
            for (int mt = 0; mt < 4; mt++)
                #pragma unroll
                for (int nt = 0; nt < 2; nt++)
                    acch[mt][nt] = __builtin_amdgcn_mfma_f32_16x16x32_bf16(af[mt], bf[nt], acch[mt][nt], 0, 0, 0);
        }
        __syncthreads();   // prev chunk's 3c reads of Hs done
        // 3b: gelu (tanh approx; output feeds *ls2=1e-5, approx error ~1e-8 in out) -> Hs
        #pragma unroll
        for (int nt = 0; nt < 2; nt++) {
            int col = w * 32 + nt * 16 + l15;
            float bb1 = b1[kc * 128 + col];
            int cg = col >> 3, ci = col & 7;
            #pragma unroll
            for (int mt = 0; mt < 4; mt++)
                #pragma unroll
                for (int rg = 0; rg < 4; rg++) {
                    int row = mt * 16 + g4 * 4 + rg;
                    float x = acch[mt][nt][rg] + bb1;
                    float u = 0.7978845608f * (x + 0.044715f * x * x * x);
                    float e = __expf(2.0f * u);
                    float gl = x - x / (e + 1.0f);     // = 0.5x(1+tanh u)
                    Hs[row * 128 + (cg ^ (row & 7)) * 8 + ci] = f2bf(gl);
                }
        }
        __syncthreads();
        // 3c: acco += Hs @ W2slice (wave w: out cols [w*64, w*64+64))
        for (int k0 = 0; k0 < 128; k0 += 32) {
            bf16x8 af[4], bf[4];
            #pragma unroll
            for (int mt = 0; mt < 4; mt++)
                af[mt] = *(const bf16x8*)(Hs + (mt * 16 + l15) * 128 + (((k0 >> 3) + g4) ^ xr) * 8);
            #pragma unroll
            for (int nt = 0; nt < 4; nt++)
                bf[nt] = *(const bf16x8*)(W2T + (size_t)(w * 64 + nt * 16 + l15) * 1024 + kc * 128 + k0 + g4 * 8);
            #pragma unroll
            for (int mt = 0; mt < 4; mt++)
                #pragma unroll
                for (int nt = 0; nt < 4; nt++)
                    acco[mt][nt] = __builtin_amdgcn_mfma_f32_16x16x32_bf16(af[mt], bf[nt], acco[mt][nt], 0, 0, 0);
        }
    }

    // phase 4: out = xa + (mlp2 + b2)*ls2, scattered
    #pragma unroll
    for (int mt = 0; mt < 4; mt++)
        #pragma unroll
        for (int rg = 0; rg < 4; rg++) {
            int row = mt * 16 + g4 * 4 + rg;
            int flat = asy[r0 + row];
            size_t orow = ((size_t)iwin[flat >> 6] * P + (flat & 63)) * C;
            #pragma unroll
            for (int nt = 0; nt < 4; nt++) {
                int col = w * 64 + nt * 16 + l15;
                float xa = bf2f(Xs[row * 256 + ((col >> 3) ^ (row & 7)) * 8 + (col & 7)]);
                out[orow + col] = xa + (acco[mt][nt][rg] + b2[col]) * ls2[col];
            }
        }
}

extern "C" void kernel_launch(void* const* d_in, const int* in_sizes, int n_in,
                              void* d_out, int out_size, void* d_ws, size_t ws_size,
                              hipStream_t stream) {
    const float* x      = (const float*)d_in[0];
    const float* qkv_w  = (const float*)d_in[1];
    const float* qkv_b  = (const float*)d_in[2];
    const float* proj_w = (const float*)d_in[3];
    const float* proj_b = (const float*)d_in[4];
    const float* n1g    = (const float*)d_in[5];
    const float* n1b    = (const float*)d_in[6];
    const float* n2g    = (const float*)d_in[7];
    const float* n2b    = (const float*)d_in[8];
    const float* ls1    = (const float*)d_in[9];
    const float* ls2    = (const float*)d_in[10];
    const float* w1     = (const float*)d_in[11];
    const float* b1     = (const float*)d_in[12];
    const float* w2     = (const float*)d_in[13];
    const float* b2     = (const float*)d_in[14];
    const int*   iwin   = (const int*)d_in[15];
    const int*   asy    = (const int*)d_in[18];
    float* out = (float*)d_out;
    u16* ws = (u16*)d_ws;

    u16* WqkvT = ws + OFF_WQKVT;
    u16* ProjT = ws + OFF_PROJT;
    u16* W1T   = ws + OFF_W1T;
    u16* W2T   = ws + OFF_W2T;
    u16* Abuf  = ws + OFF_A;
    u16* QKV   = ws + OFF_QKV;
    u16* AttnO = ws + OFF_ATTNO;

    prep_weights<<<3072, 256, 0, stream>>>(qkv_w, proj_w, w1, w2, ws);
    ln1_kernel<<<(NWIN * P) / 4, 256, 0, stream>>>(x, n1g, n1b, out);
    ln2_kernel<<<MROWS / 4, 256, 0, stream>>>(out, n2g, n2b, asy, iwin, Abuf);
    {
        int nwg = (MROWS / 128) * 6;
        gemm_bt<768, 256, EpiQKV><<<nwg, 256, 0, stream>>>(Abuf, WqkvT, EpiQKV{qkv_b, QKV}, nwg / 8);
    }
    attn_kernel<<<MSEL, 256, 0, stream>>>(QKV, AttnO);
    fused_tail<<<MROWS / 64, 256, 0, stream>>>(AttnO, Abuf, ProjT, W1T, W2T,
                                               proj_b, ls1, b1, b2, ls2, asy, iwin, out);
}

// Round 5
// 575.021 us; speedup vs baseline: 1.0905x; 1.0905x over previous
//
#include <hip/hip_runtime.h>

typedef __attribute__((ext_vector_type(8))) short bf16x8;
typedef __attribute__((ext_vector_type(4))) float f32x4;
typedef unsigned short u16;
typedef unsigned int u32;
typedef unsigned char u8;

// ---------- constants ----------
#define NWIN 2048
#define P 64
#define C 256
#define MSEL 1536
#define KEEP 48
#define REAL 40
#define H 8
#define DH 32
#define MROWS (MSEL * REAL)          // 61440 compacted rows

// ws BYTE offsets (16B aligned)
#define B_WQKVT   0                  // bf16 [768][256]   393216
#define B_W1T     393216             // bf16 [1024][256]  524288
#define B_PROJT8  917504             // fp8  [256][256]    65536
#define B_W2T8    983040             // fp8  [256][1024]  262144
#define B_INV     1245184            // i32  [131072]     524288
#define B_ABUF    1769472            // bf16 [61440][256] 31457280
#define B_XA      33226752           // bf16 [61440][256] 31457280
#define B_QKV8    64684032           // fp8  [61440][768] 47185920
#define B_ATTNO8  111869952          // fp8  [61440][256] 15728640
#define B_H8      64684032           // fp8  [61440][1024] aliases QKV8+AttnO8 (dead)

__device__ __forceinline__ u16 f2bf(float f) {
    u32 u = __float_as_uint(f);
    u += 0x7FFF + ((u >> 16) & 1);   // RNE
    return (u16)(u >> 16);
}
__device__ __forceinline__ float bf2f(u16 h) { return __uint_as_float(((u32)h) << 16); }
__device__ __forceinline__ u8 f2fp8(float f) {   // e4m3fn (hw native on gfx950), RNE+sat
    return (u8)__builtin_amdgcn_cvt_pk_fp8_f32(f, 0.0f, 0, false);
}

// ---------- prep: weights -> bf16/fp8 transposed; inv map init ----------
__global__ __launch_bounds__(256) void prep_weights(const float* __restrict__ qkv_w,
                                                    const float* __restrict__ proj_w,
                                                    const float* __restrict__ w1,
                                                    const float* __restrict__ w2,
                                                    u8* __restrict__ ws) {
    int i = blockIdx.x * 256 + threadIdx.x;   // 917504 total
    if (i < 196608) {                                      // WqkvT bf16 [768][256]
        int n = i >> 8, k = i & 255;
        ((u16*)(ws + B_WQKVT))[i] = f2bf(qkv_w[k * 768 + n]);
    } else if (i < 458752) {                               // W1T bf16 [1024][256]
        int j = i - 196608; int n = j >> 8, k = j & 255;
        ((u16*)(ws + B_W1T))[j] = f2bf(w1[k * 1024 + n]);
    } else if (i < 524288) {                               // ProjT8 [256][256]
        int j = i - 458752; int n = j >> 8, k = j & 255;
        (ws + B_PROJT8)[j] = f2fp8(proj_w[k * 256 + n]);
    } else if (i < 786432) {                               // W2T8 [256][1024]
        int j = i - 524288; int n = j >> 10, k = j & 1023;
        (ws + B_W2T8)[j] = f2fp8(w2[k * 256 + n]);
    } else {                                               // inv = -1
        ((int*)(ws + B_INV))[i - 786432] = -1;
    }
}

__global__ __launch_bounds__(256) void build_inv(const int* __restrict__ asy,
                                                 const int* __restrict__ iwin,
                                                 int* __restrict__ inv) {
    int r = blockIdx.x * 256 + threadIdx.x;   // 61440
    int flat = asy[r];
    inv[iwin[flat >> 6] * P + (flat & 63)] = r;
}

// ---------- fused LN1 (all rows -> out fp32) + LN2 (mapped rows -> Abuf bf16) ----------
__global__ __launch_bounds__(256) void ln12_kernel(const float* __restrict__ x,
                                                   const float* __restrict__ g1,
                                                   const float* __restrict__ b1,
                                                   const float* __restrict__ g2,
                                                   const float* __restrict__ b2,
                                                   const int* __restrict__ inv,
                                                   float* __restrict__ out,
                                                   u16* __restrict__ Abuf) {
    int row = blockIdx.x * 4 + (threadIdx.x >> 6);
    int l = threadIdx.x & 63;
    const float4 v = *(const float4*)(x + (size_t)row * C + l * 4);
    float s = v.x + v.y + v.z + v.w;
    float q = v.x * v.x + v.y * v.y + v.z * v.z + v.w * v.w;
    #pragma unroll
    for (int m = 1; m < 64; m <<= 1) { s += __shfl_xor(s, m); q += __shfl_xor(q, m); }
    float mu = s * (1.0f / C);
    float rs = rsqrtf(q * (1.0f / C) - mu * mu + 1e-5f);
    float4 gg = *(const float4*)(g1 + l * 4);
    float4 bb = *(const float4*)(b1 + l * 4);
    float4 o;
    o.x = (v.x - mu) * rs * gg.x + bb.x;
    o.y = (v.y - mu) * rs * gg.y + bb.y;
    o.z = (v.z - mu) * rs * gg.z + bb.z;
    o.w = (v.w - mu) * rs * gg.w + bb.w;
    *(float4*)(out + (size_t)row * C + l * 4) = o;
    int r = inv[row];                       // wave-uniform
    if (r >= 0) {
        float s2 = o.x + o.y + o.z + o.w;
        float q2 = o.x * o.x + o.y * o.y + o.z * o.z + o.w * o.w;
        #pragma unroll
        for (int m = 1; m < 64; m <<= 1) { s2 += __shfl_xor(s2, m); q2 += __shfl_xor(q2, m); }
        float mu2 = s2 * (1.0f / C);
        float rs2 = rsqrtf(q2 * (1.0f / C) - mu2 * mu2 + 1e-5f);
        float4 g2v = *(const float4*)(g2 + l * 4);
        float4 b2v = *(const float4*)(b2 + l * 4);
        ushort4 ob;
        ob.x = f2bf((o.x - mu2) * rs2 * g2v.x + b2v.x);
        ob.y = f2bf((o.y - mu2) * rs2 * g2v.y + b2v.y);
        ob.z = f2bf((o.z - mu2) * rs2 * g2v.z + b2v.z);
        ob.w = f2bf((o.w - mu2) * rs2 * g2v.w + b2v.w);
        *(ushort4*)(Abuf + (size_t)r * C + l * 4) = ob;
    }
}

// ---------- bf16 128x128 GEMM (m97 structure): C = A[MxK] * B^T[NxK] ----------
template <int N, int K, class Epi>
__global__ __launch_bounds__(256) void gemm_bt(const u16* __restrict__ A,
                                               const u16* __restrict__ B, Epi epi,
                                               int chunk) {
    constexpr int NB = N / 128;
    int bid = blockIdx.x;
    bid = (bid & 7) * chunk + (bid >> 3);          // XCD swizzle (grid % 8 == 0)
    int bm = bid / NB, bn = bid % NB;
    __shared__ u16 lA[128 * 64], lB[128 * 64];
    int t = threadIdx.x;
    int l = t & 63, w = t >> 6;
    int wr = w >> 1, wc = w & 1;
    int l15 = l & 15, g4 = l >> 4;
    int xr = l15 & 7;

    f32x4 acc[4][4];
    #pragma unroll
    for (int a = 0; a < 4; a++)
        #pragma unroll
        for (int bb = 0; bb < 4; bb++)
            #pragma unroll
            for (int i = 0; i < 4; i++) acc[a][bb][i] = 0.0f;

    int rbase = w * 32 + (l >> 3);
    int cg = (l & 7) ^ (l >> 3);
    const u16* gA = A + (size_t)(bm * 128 + rbase) * K + cg * 8;
    const u16* gB = B + (size_t)(bn * 128 + rbase) * K + cg * 8;

    for (int k0 = 0; k0 < K; k0 += 64) {
        __syncthreads();
        #pragma unroll
        for (int j = 0; j < 4; j++)
            __builtin_amdgcn_global_load_lds(
                (const __attribute__((address_space(1))) u32*)(gA + (size_t)j * 8 * K + k0),
                (__attribute__((address_space(3))) u32*)(lA + w * 2048 + j * 512), 16, 0, 0);
        #pragma unroll
        for (int j = 0; j < 4; j++)
            __builtin_amdgcn_global_load_lds(
                (const __attribute__((address_space(1))) u32*)(gB + (size_t)j * 8 * K + k0),
                (__attribute__((address_space(3))) u32*)(lB + w * 2048 + j * 512), 16, 0, 0);
        __syncthreads();
        #pragma unroll
        for (int kk = 0; kk < 2; kk++) {
            bf16x8 af[4], bfr[4];
            #pragma unroll
            for (int mt = 0; mt < 4; mt++)
                af[mt] = *(const bf16x8*)(lA + (wr * 64 + mt * 16 + l15) * 64
                                             + ((kk * 4 + g4) ^ xr) * 8);
            #pragma unroll
            for (int nt = 0; nt < 4; nt++)
                bfr[nt] = *(const bf16x8*)(lB + (wc * 64 + nt * 16 + l15) * 64
                                              + ((kk * 4 + g4) ^ xr) * 8);
            #pragma unroll
            for (int mt = 0; mt < 4; mt++)
                #pragma unroll
                for (int nt = 0; nt < 4; nt++)
                    acc[mt][nt] = __builtin_amdgcn_mfma_f32_16x16x32_bf16(af[mt], bfr[nt], acc[mt][nt], 0, 0, 0);
        }
    }
    int orow = bm * 128 + wr * 64, ocol = bn * 128 + wc * 64;
    #pragma unroll
    for (int mt = 0; mt < 4; mt++)
        #pragma unroll
        for (int nt = 0; nt < 4; nt++)
            #pragma unroll
            for (int rg = 0; rg < 4; rg++)
                epi(orow + mt * 16 + g4 * 4 + rg, ocol + nt * 16 + l15, acc[mt][nt][rg]);
}

// ---------- fp8 128x128 GEMM: C = A[MxK] * B^T[NxK], A/B e4m3 ----------
template <int N, int K, class Epi>
__global__ __launch_bounds__(256) void gemm_bt8(const u8* __restrict__ A,
                                                const u8* __restrict__ B, Epi epi,
                                                int chunk) {
    constexpr int NB = N / 128;
    int bid = blockIdx.x;
    bid = (bid & 7) * chunk + (bid >> 3);
    int bm = bid / NB, bn = bid % NB;
    __shared__ u8 lA[128 * 64], lB[128 * 64];    // 8KB each
    int t = threadIdx.x;
    int l = t & 63, w = t >> 6;
    int wr = w >> 1, wc = w & 1;
    int l15 = l & 15, g4 = l >> 4;
    int xr3 = l15 & 3;

    f32x4 acc[4][4];
    #pragma unroll
    for (int a = 0; a < 4; a++)
        #pragma unroll
        for (int bb = 0; bb < 4; bb++)
            #pragma unroll
            for (int i = 0; i < 4; i++) acc[a][bb][i] = 0.0f;

    // staging: wave w fills bytes [w*2KB,(w+1)*2KB), 2 issues of 1KB (lane: 16B)
    // linear byte off = w*2048 + j*1024 + l*16 -> row = w*32 + j*16 + (l>>2), grp16 = l&3
    int rbase = w * 32 + (l >> 2);
    int sx = (l & 3) ^ ((l >> 2) & 3);            // pre-swizzled source 16B-group
    const u8* gA = A + (size_t)(bm * 128 + rbase) * K + sx * 16;
    const u8* gB = B + (size_t)(bn * 128 + rbase) * K + sx * 16;

    for (int k0 = 0; k0 < K; k0 += 64) {
        __syncthreads();
        #pragma unroll
        for (int j = 0; j < 2; j++)
            __builtin_amdgcn_global_load_lds(
                (const __attribute__((address_space(1))) u32*)(gA + (size_t)j * 16 * K + k0),
                (__attribute__((address_space(3))) u32*)(lA + w * 2048 + j * 1024), 16, 0, 0);
        #pragma unroll
        for (int j = 0; j < 2; j++)
            __builtin_amdgcn_global_load_lds(
                (const __attribute__((address_space(1))) u32*)(gB + (size_t)j * 16 * K + k0),
                (__attribute__((address_space(3))) u32*)(lB + w * 2048 + j * 1024), 16, 0, 0);
        __syncthreads();
        #pragma unroll
        for (int kk = 0; kk < 2; kk++) {
            long af[4], bfr[4];
            #pragma unroll
            for (int mt = 0; mt < 4; mt++) {
                int r = wr * 64 + mt * 16 + l15;
                af[mt] = *(const long*)(lA + r * 64 + (((kk * 2) + (g4 >> 1)) ^ xr3) * 16 + (g4 & 1) * 8);
            }
            #pragma unroll
            for (int nt = 0; nt < 4; nt++) {
                int r = wc * 64 + nt * 16 + l15;
                bfr[nt] = *(const long*)(lB + r * 64 + (((kk * 2) + (g4 >> 1)) ^ xr3) * 16 + (g4 & 1) * 8);
            }
            #pragma unroll
            for (int mt = 0; mt < 4; mt++)
                #pragma unroll
                for (int nt = 0; nt < 4; nt++)
                    acc[mt][nt] = __builtin_amdgcn_mfma_f32_16x16x32_fp8_fp8(af[mt], bfr[nt], acc[mt][nt], 0, 0, 0);
        }
    }
    int orow = bm * 128 + wr * 64, ocol = bn * 128 + wc * 64;
    #pragma unroll
    for (int mt = 0; mt < 4; mt++)
        #pragma unroll
        for (int nt = 0; nt < 4; nt++)
            #pragma unroll
            for (int rg = 0; rg < 4; rg++)
                epi(orow + mt * 16 + g4 * 4 + rg, ocol + nt * 16 + l15, acc[mt][nt][rg]);
}

struct EpiQKV8 {
    const float* bias; u8* out;
    __device__ void operator()(int r, int c, float v) const {
        out[(size_t)r * 768 + c] = f2fp8(v + bias[c]);
    }
};
struct EpiProj {
    const float* bias; const float* ls1; const u16* Abuf; u16* xa;
    __device__ void operator()(int r, int c, float v) const {
        float val = bf2f(Abuf[(size_t)r * 256 + c]) + (v + bias[c]) * ls1[c];
        xa[(size_t)r * 256 + c] = f2bf(val);
    }
};
struct EpiMLP1 {
    const float* bias; u8* h;
    __device__ void operator()(int r, int c, float v) const {
        float x = v + bias[c];
        float u = 0.7978845608f * (x + 0.044715f * x * x * x);
        float e = __expf(2.0f * u);
        h[(size_t)r * 1024 + c] = f2fp8(x - x / (e + 1.0f));   // 0.5x(1+tanh u)
    }
};
struct EpiMLP2 {
    const float* bias; const float* ls2; const u16* xa;
    const int* asy; const int* iwin; float* out;
    __device__ void operator()(int r, int c, float v) const {
        float val = bf2f(xa[(size_t)r * 256 + c]) + (v + bias[c]) * ls2[c];
        int flat = asy[r];
        out[((size_t)iwin[flat >> 6] * P + (flat & 63)) * C + c] = val;
    }
};

// ---------- fused per-window attention (fp8 in / fp8 out) ----------
// 1 block / window, 4 waves, 2 heads per wave. Q/K/V e4m3; softmax fp32; P stored e4m3.
__global__ __launch_bounds__(256) void attn_kernel(const u8* __restrict__ QKV,
                                                   u8* __restrict__ out) {
    __shared__ u8 lds[4 * (48 * 80 + 32 * 80)];   // per wave: Pb[48][80] + Vt[32][80]
    int m = blockIdx.x;
    int t = threadIdx.x, l = t & 63, w = t >> 6;
    int l15 = l & 15, g4 = l >> 4;
    u8* Pb = lds + w * (48 * 80 + 32 * 80);
    u8* Vt = Pb + 48 * 80;

    u32* z = (u32*)Pb;
    for (int i = l; i < (48 * 80 + 32 * 80) / 4; i += 64) z[i] = 0;

    const float scale = 0.17677669529663687f; // 32^-0.5

    for (int hh = 0; hh < 2; hh++) {
        int h = w + hh * 4;
        const u8* base = QKV + (size_t)m * REAL * 768 + h * 96;

        // stage V^T[d][key] (keys >=40 stay zero)
        for (int i = l; i < REAL * 8; i += 64) {
            int kk = i >> 3, dg = i & 7;
            u32 vv = *(const u32*)(base + (size_t)kk * 768 + 64 + dg * 4);
            #pragma unroll
            for (int j = 0; j < 4; j++) Vt[(dg * 4 + j) * 80 + kk] = (u8)(vv >> (j * 8));
        }

        long qf[3], kf[3];
        #pragma unroll
        for (int mt = 0; mt < 3; mt++) {
            int q = mt * 16 + l15;
            qf[mt] = (q < REAL) ? *(const long*)(base + (size_t)q * 768 + g4 * 8) : 0L;
        }
        #pragma unroll
        for (int nt = 0; nt < 3; nt++) {
            int kk = nt * 16 + l15;
            kf[nt] = (kk < REAL) ? *(const long*)(base + (size_t)kk * 768 + 32 + g4 * 8) : 0L;
        }
        f32x4 s[3][3];
        #pragma unroll
        for (int a = 0; a < 3; a++)
            #pragma unroll
            for (int bb = 0; bb < 3; bb++)
                #pragma unroll
                for (int i = 0; i < 4; i++) s[a][bb][i] = 0.0f;
        #pragma unroll
        for (int mt = 0; mt < 3; mt++)
            #pragma unroll
            for (int nt = 0; nt < 3; nt++)
                s[mt][nt] = __builtin_amdgcn_mfma_f32_16x16x32_fp8_fp8(qf[mt], kf[nt], s[mt][nt], 0, 0, 0);

        // masked softmax; P -> e4m3 (keys 40..47 exact 0)
        #pragma unroll
        for (int mt = 0; mt < 3; mt++) {
            #pragma unroll
            for (int rg = 0; rg < 4; rg++) {
                float v0 = s[mt][0][rg] * scale;
                float v1 = s[mt][1][rg] * scale;
                float v2 = s[mt][2][rg] * scale;
                bool k2ok = (32 + l15) < REAL;
                float mx = fmaxf(fmaxf(v0, v1), k2ok ? v2 : -1e30f);
                #pragma unroll
                for (int xm = 1; xm < 16; xm <<= 1) mx = fmaxf(mx, __shfl_xor(mx, xm));
                float e0 = __expf(v0 - mx);
                float e1 = __expf(v1 - mx);
                float e2 = k2ok ? __expf(v2 - mx) : 0.0f;
                float sm = e0 + e1 + e2;
                #pragma unroll
                for (int xm = 1; xm < 16; xm <<= 1) sm += __shfl_xor(sm, xm);
                float inv = 1.0f / sm;
                int q = mt * 16 + g4 * 4 + rg;
                Pb[q * 80 + l15]      = f2fp8(e0 * inv);
                Pb[q * 80 + 16 + l15] = f2fp8(e1 * inv);
                Pb[q * 80 + 32 + l15] = k2ok ? f2fp8(e2 * inv) : (u8)0;
            }
        }

        f32x4 o[3][2];
        #pragma unroll
        for (int a = 0; a < 3; a++)
            #pragma unroll
            for (int bb = 0; bb < 2; bb++)
                #pragma unroll
                for (int i = 0; i < 4; i++) o[a][bb][i] = 0.0f;
        #pragma unroll
        for (int kt = 0; kt < 2; kt++) {
            long pf[3], vf[2];
            #pragma unroll
            for (int mt = 0; mt < 3; mt++)
                pf[mt] = *(const long*)(Pb + (mt * 16 + l15) * 80 + kt * 32 + g4 * 8);
            #pragma unroll
            for (int nt = 0; nt < 2; nt++)
                vf[nt] = *(const long*)(Vt + (nt * 16 + l15) * 80 + kt * 32 + g4 * 8);
            #pragma unroll
            for (int mt = 0; mt < 3; mt++)
                #pragma unroll
                for (int nt = 0; nt < 2; nt++)
                    o[mt][nt] = __builtin_amdgcn_mfma_f32_16x16x32_fp8_fp8(pf[mt], vf[nt], o[mt][nt], 0, 0, 0);
        }
        #pragma unroll
        for (int mt = 0; mt < 3; mt++)
            #pragma unroll
            for (int nt = 0; nt < 2; nt++)
                #pragma unroll
                for (int rg = 0; rg < 4; rg++) {
                    int q = mt * 16 + g4 * 4 + rg;
                    if (q < REAL)
                        out[((size_t)m * REAL + q) * C + h * DH + nt * 16 + l15] = f2fp8(o[mt][nt][rg]);
                }
    }
}

extern "C" void kernel_launch(void* const* d_in, const int* in_sizes, int n_in,
                              void* d_out, int out_size, void* d_ws, size_t ws_size,
                              hipStream_t stream) {
    const float* x      = (const float*)d_in[0];
    const float* qkv_w  = (const float*)d_in[1];
    const float* qkv_b  = (const float*)d_in[2];
    const float* proj_w = (const float*)d_in[3];
    const float* proj_b = (const float*)d_in[4];
    const float* n1g    = (const float*)d_in[5];
    const float* n1b    = (const float*)d_in[6];
    const float* n2g    = (const float*)d_in[7];
    const float* n2b    = (const float*)d_in[8];
    const float* ls1    = (const float*)d_in[9];
    const float* ls2    = (const float*)d_in[10];
    const float* w1     = (const float*)d_in[11];
    const float* b1     = (const float*)d_in[12];
    const float* w2     = (const float*)d_in[13];
    const float* b2     = (const float*)d_in[14];
    const int*   iwin   = (const int*)d_in[15];
    const int*   asy    = (const int*)d_in[18];
    float* out = (float*)d_out;
    u8* ws = (u8*)d_ws;

    u16* WqkvT  = (u16*)(ws + B_WQKVT);
    u16* W1T    = (u16*)(ws + B_W1T);
    u8*  ProjT8 = ws + B_PROJT8;
    u8*  W2T8   = ws + B_W2T8;
    int* inv    = (int*)(ws + B_INV);
    u16* Abuf   = (u16*)(ws + B_ABUF);
    u16* XA     = (u16*)(ws + B_XA);
    u8*  QKV8   = ws + B_QKV8;
    u8*  AttnO8 = ws + B_ATTNO8;
    u8*  H8     = ws + B_H8;          // aliases QKV8+AttnO8 (dead by MLP1)

    prep_weights<<<3584, 256, 0, stream>>>(qkv_w, proj_w, w1, w2, ws);
    build_inv<<<240, 256, 0, stream>>>(asy, iwin, inv);
    ln12_kernel<<<(NWIN * P) / 4, 256, 0, stream>>>(x, n1g, n1b, n2g, n2b, inv, out, Abuf);
    {
        int nwg = (MROWS / 128) * 6;
        gemm_bt<768, 256, EpiQKV8><<<nwg, 256, 0, stream>>>(Abuf, WqkvT, EpiQKV8{qkv_b, QKV8}, nwg / 8);
    }
    attn_kernel<<<MSEL, 256, 0, stream>>>(QKV8, AttnO8);
    {
        int nwg = (MROWS / 128) * 2;
        gemm_bt8<256, 256, EpiProj><<<nwg, 256, 0, stream>>>(AttnO8, ProjT8, EpiProj{proj_b, ls1, Abuf, XA}, nwg / 8);
    }
    {
        int nwg = (MROWS / 128) * 8;
        gemm_bt<1024, 256, EpiMLP1><<<nwg, 256, 0, stream>>>(XA, W1T, EpiMLP1{b1, H8}, nwg / 8);
    }
    {
        int nwg = (MROWS / 128) * 2;
        gemm_bt8<256, 1024, EpiMLP2><<<nwg, 256, 0, stream>>>(H8, W2T8, EpiMLP2{b2, ls2, XA, asy, iwin, out}, nwg / 8);
    }
}

// Round 6
// 476.285 us; speedup vs baseline: 1.3166x; 1.2073x over previous
//
#include <hip/hip_runtime.h>

typedef __attribute__((ext_vector_type(8))) short bf16x8;
typedef __attribute__((ext_vector_type(4))) float f32x4;
typedef unsigned short u16;
typedef unsigned int u32;
typedef unsigned char u8;

// ---------- constants ----------
#define NWIN 2048
#define P 64
#define C 256
#define MSEL 1536
#define KEEP 48
#define REAL 40
#define H 8
#define DH 32
#define MROWS (MSEL * REAL)          // 61440 compacted rows

// ws BYTE offsets (16B aligned)
#define B_WQKVT   0                  // bf16 [768][256]   393216
#define B_W1T     393216             // bf16 [1024][256]  524288
#define B_PROJT8  917504             // fp8  [256][256]    65536
#define B_W2T8    983040             // fp8  [256][1024]  262144
#define B_INV     1245184            // i32  [131072]     524288
#define B_ABUF    1769472            // bf16 [61440][256] 31457280
#define B_XA      33226752           // bf16 [61440][256] 31457280
#define B_QKV8    64684032           // fp8  [61440][768] 47185920
#define B_ATTNO8  111869952          // fp8  [61440][256] 15728640
#define B_H8      64684032           // fp8  [61440][1024] aliases QKV8+AttnO8 (dead)

__device__ __forceinline__ u16 f2bf(float f) {
    u32 u = __float_as_uint(f);
    u += 0x7FFF + ((u >> 16) & 1);   // RNE
    return (u16)(u >> 16);
}
__device__ __forceinline__ float bf2f(u16 h) { return __uint_as_float(((u32)h) << 16); }
__device__ __forceinline__ u8 f2fp8(float f) {
    return (u8)__builtin_amdgcn_cvt_pk_fp8_f32(f, 0.0f, 0, false);
}
// sigmoid-GELU: error << fp8 quantization of H; scaled by ls2=1e-5 downstream
__device__ __forceinline__ float gelu_s(float x) {
    return x * __builtin_amdgcn_rcpf(1.0f + __expf(-1.702f * x));
}
// stored-pos permutations (K-relabel): p32(c) = (c%16)*2 + c/16 on [0,32)
__device__ __forceinline__ int pinv32(int s) { return (s & 1) * 16 + (s >> 1); }

// ---------- prep: weights (K-permuted where needed); inv map init ----------
__global__ __launch_bounds__(256) void prep_weights(const float* __restrict__ qkv_w,
                                                    const float* __restrict__ proj_w,
                                                    const float* __restrict__ w1,
                                                    const float* __restrict__ w2,
                                                    u8* __restrict__ ws) {
    int i = blockIdx.x * 256 + threadIdx.x;   // 917504 total
    if (i < 196608) {                                      // WqkvT bf16 [768][256] (logical)
        int n = i >> 8, k = i & 255;
        ((u16*)(ws + B_WQKVT))[i] = f2bf(qkv_w[k * 768 + n]);
    } else if (i < 458752) {                               // W1T bf16 [1024][256] (logical)
        int j = i - 196608; int n = j >> 8, k = j & 255;
        ((u16*)(ws + B_W1T))[j] = f2bf(w1[k * 1024 + n]);
    } else if (i < 524288) {                               // ProjT8 [256][256], K rows double-permuted
        int j = i - 458752; int n = j >> 8, rk = j & 255;
        int h = rk >> 5, s = rk & 31;
        int d = pinv32(pinv32(s));                         // AttnO stored pos -> logical d
        (ws + B_PROJT8)[j] = f2fp8(proj_w[(h * 32 + d) * 256 + n]);
    } else if (i < 786432) {                               // W2T8 [256][1024], K rows pi64-permuted
        int j = i - 524288; int n = j >> 10, ks = j & 1023;
        int grp = ks >> 6, pos = ks & 63;
        int k = grp * 64 + (pos & 3) * 16 + (pos >> 2);    // H stored pos -> logical k
        (ws + B_W2T8)[j] = f2fp8(w2[k * 256 + n]);
    } else {                                               // inv = -1
        ((int*)(ws + B_INV))[i - 786432] = -1;
    }
}

__global__ __launch_bounds__(256) void build_inv(const int* __restrict__ asy,
                                                 const int* __restrict__ iwin,
                                                 int* __restrict__ inv) {
    int r = blockIdx.x * 256 + threadIdx.x;   // 61440
    int flat = asy[r];
    inv[iwin[flat >> 6] * P + (flat & 63)] = r;
}

// ---------- fused LN1 + LN2; skip fp32 writes for rows MLP2 will overwrite ----------
__global__ __launch_bounds__(256) void ln12_kernel(const float* __restrict__ x,
                                                   const float* __restrict__ g1,
                                                   const float* __restrict__ b1,
                                                   const float* __restrict__ g2,
                                                   const float* __restrict__ b2,
                                                   const int* __restrict__ inv,
                                                   float* __restrict__ out,
                                                   u16* __restrict__ Abuf) {
    int row = blockIdx.x * 4 + (threadIdx.x >> 6);
    int l = threadIdx.x & 63;
    const float4 v = *(const float4*)(x + (size_t)row * C + l * 4);
    float s = v.x + v.y + v.z + v.w;
    float q = v.x * v.x + v.y * v.y + v.z * v.z + v.w * v.w;
    #pragma unroll
    for (int m = 1; m < 64; m <<= 1) { s += __shfl_xor(s, m); q += __shfl_xor(q, m); }
    float mu = s * (1.0f / C);
    float rs = rsqrtf(q * (1.0f / C) - mu * mu + 1e-5f);
    float4 gg = *(const float4*)(g1 + l * 4);
    float4 bb = *(const float4*)(b1 + l * 4);
    float4 o;
    o.x = (v.x - mu) * rs * gg.x + bb.x;
    o.y = (v.y - mu) * rs * gg.y + bb.y;
    o.z = (v.z - mu) * rs * gg.z + bb.z;
    o.w = (v.w - mu) * rs * gg.w + bb.w;
    int r = inv[row];                       // wave-uniform
    if (r < 0) {
        *(float4*)(out + (size_t)row * C + l * 4) = o;   // kept rows get overwritten by MLP2
    } else {
        float s2 = o.x + o.y + o.z + o.w;
        float q2 = o.x * o.x + o.y * o.y + o.z * o.z + o.w * o.w;
        #pragma unroll
        for (int m = 1; m < 64; m <<= 1) { s2 += __shfl_xor(s2, m); q2 += __shfl_xor(q2, m); }
        float mu2 = s2 * (1.0f / C);
        float rs2 = rsqrtf(q2 * (1.0f / C) - mu2 * mu2 + 1e-5f);
        float4 g2v = *(const float4*)(g2 + l * 4);
        float4 b2v = *(const float4*)(b2 + l * 4);
        ushort4 ob;
        ob.x = f2bf((o.x - mu2) * rs2 * g2v.x + b2v.x);
        ob.y = f2bf((o.y - mu2) * rs2 * g2v.y + b2v.y);
        ob.z = f2bf((o.z - mu2) * rs2 * g2v.z + b2v.z);
        ob.w = f2bf((o.w - mu2) * rs2 * g2v.w + b2v.w);
        *(ushort4*)(Abuf + (size_t)r * C + l * 4) = ob;
    }
}

// ---------- bf16 128x128 GEMM (m97 structure): C = A[MxK] * B^T[NxK] ----------
template <int N, int K, class Epi>
__global__ __launch_bounds__(256) void gemm_bt(const u16* __restrict__ A,
                                               const u16* __restrict__ B, Epi epi,
                                               int chunk) {
    constexpr int NB = N / 128;
    int bid = blockIdx.x;
    bid = (bid & 7) * chunk + (bid >> 3);          // XCD swizzle (grid % 8 == 0)
    int bm = bid / NB, bn = bid % NB;
    __shared__ u16 lA[128 * 64], lB[128 * 64];
    int t = threadIdx.x;
    int l = t & 63, w = t >> 6;
    int wr = w >> 1, wc = w & 1;
    int l15 = l & 15, g4 = l >> 4;
    int xr = l15 & 7;

    f32x4 acc[4][4];
    #pragma unroll
    for (int a = 0; a < 4; a++)
        #pragma unroll
        for (int bb = 0; bb < 4; bb++)
            #pragma unroll
            for (int i = 0; i < 4; i++) acc[a][bb][i] = 0.0f;

    int rbase = w * 32 + (l >> 3);
    int cg = (l & 7) ^ (l >> 3);
    const u16* gA = A + (size_t)(bm * 128 + rbase) * K + cg * 8;
    const u16* gB = B + (size_t)(bn * 128 + rbase) * K + cg * 8;

    for (int k0 = 0; k0 < K; k0 += 64) {
        __syncthreads();
        #pragma unroll
        for (int j = 0; j < 4; j++)
            __builtin_amdgcn_global_load_lds(
                (const __attribute__((address_space(1))) u32*)(gA + (size_t)j * 8 * K + k0),
                (__attribute__((address_space(3))) u32*)(lA + w * 2048 + j * 512), 16, 0, 0);
        #pragma unroll
        for (int j = 0; j < 4; j++)
            __builtin_amdgcn_global_load_lds(
                (const __attribute__((address_space(1))) u32*)(gB + (size_t)j * 8 * K + k0),
                (__attribute__((address_space(3))) u32*)(lB + w * 2048 + j * 512), 16, 0, 0);
        __syncthreads();
        #pragma unroll
        for (int kk = 0; kk < 2; kk++) {
            bf16x8 af[4], bfr[4];
            #pragma unroll
            for (int mt = 0; mt < 4; mt++)
                af[mt] = *(const bf16x8*)(lA + (wr * 64 + mt * 16 + l15) * 64
                                             + ((kk * 4 + g4) ^ xr) * 8);
            #pragma unroll
            for (int nt = 0; nt < 4; nt++)
                bfr[nt] = *(const bf16x8*)(lB + (wc * 64 + nt * 16 + l15) * 64
                                              + ((kk * 4 + g4) ^ xr) * 8);
            #pragma unroll
            for (int mt = 0; mt < 4; mt++)
                #pragma unroll
                for (int nt = 0; nt < 4; nt++)
                    acc[mt][nt] = __builtin_amdgcn_mfma_f32_16x16x32_bf16(af[mt], bfr[nt], acc[mt][nt], 0, 0, 0);
        }
    }
    epi.store(bm * 128 + wr * 64, bn * 128 + wc * 64, l15, g4, acc);
}

// ---------- fp8 128x128 GEMM: C = A[MxK] * B^T[NxK], A/B e4m3 ----------
template <int N, int K, class Epi>
__global__ __launch_bounds__(256) void gemm_bt8(const u8* __restrict__ A,
                                                const u8* __restrict__ B, Epi epi,
                                                int chunk) {
    constexpr int NB = N / 128;
    int bid = blockIdx.x;
    bid = (bid & 7) * chunk + (bid >> 3);
    int bm = bid / NB, bn = bid % NB;
    __shared__ u8 lA[128 * 64], lB[128 * 64];
    int t = threadIdx.x;
    int l = t & 63, w = t >> 6;
    int wr = w >> 1, wc = w & 1;
    int l15 = l & 15, g4 = l >> 4;
    int xr3 = l15 & 3;

    f32x4 acc[4][4];
    #pragma unroll
    for (int a = 0; a < 4; a++)
        #pragma unroll
        for (int bb = 0; bb < 4; bb++)
            #pragma unroll
            for (int i = 0; i < 4; i++) acc[a][bb][i] = 0.0f;

    int rbase = w * 32 + (l >> 2);
    int sx = (l & 3) ^ ((l >> 2) & 3);
    const u8* gA = A + (size_t)(bm * 128 + rbase) * K + sx * 16;
    const u8* gB = B + (size_t)(bn * 128 + rbase) * K + sx * 16;

    for (int k0 = 0; k0 < K; k0 += 64) {
        __syncthreads();
        #pragma unroll
        for (int j = 0; j < 2; j++)
            __builtin_amdgcn_global_load_lds(
                (const __attribute__((address_space(1))) u32*)(gA + (size_t)j * 16 * K + k0),
                (__attribute__((address_space(3))) u32*)(lA + w * 2048 + j * 1024), 16, 0, 0);
        #pragma unroll
        for (int j = 0; j < 2; j++)
            __builtin_amdgcn_global_load_lds(
                (const __attribute__((address_space(1))) u32*)(gB + (size_t)j * 16 * K + k0),
                (__attribute__((address_space(3))) u32*)(lB + w * 2048 + j * 1024), 16, 0, 0);
        __syncthreads();
        #pragma unroll
        for (int kk = 0; kk < 2; kk++) {
            long af[4], bfr[4];
            #pragma unroll
            for (int mt = 0; mt < 4; mt++) {
                int r = wr * 64 + mt * 16 + l15;
                af[mt] = *(const long*)(lA + r * 64 + (((kk * 2) + (g4 >> 1)) ^ xr3) * 16 + (g4 & 1) * 8);
            }
            #pragma unroll
            for (int nt = 0; nt < 4; nt++) {
                int r = wc * 64 + nt * 16 + l15;
                bfr[nt] = *(const long*)(lB + r * 64 + (((kk * 2) + (g4 >> 1)) ^ xr3) * 16 + (g4 & 1) * 8);
            }
            #pragma unroll
            for (int mt = 0; mt < 4; mt++)
                #pragma unroll
                for (int nt = 0; nt < 4; nt++)
                    acc[mt][nt] = __builtin_amdgcn_mfma_f32_16x16x32_fp8_fp8(af[mt], bfr[nt], acc[mt][nt], 0, 0, 0);
        }
    }
    epi.store(bm * 128 + wr * 64, bn * 128 + wc * 64, l15, g4, acc);
}

// ---- epilogues (block-store interface; fp8 outputs packed, K-relabeled) ----
struct EpiQKV8 {   // pi32 u16-pair packed fp8
    const float* bias; u8* out;
    __device__ void store(int orow, int ocol, int l15, int g4, const f32x4 (&acc)[4][4]) const {
        float b[4];
        #pragma unroll
        for (int nt = 0; nt < 4; nt++) b[nt] = bias[ocol + nt * 16 + l15];
        #pragma unroll
        for (int mt = 0; mt < 4; mt++)
            #pragma unroll
            for (int rg = 0; rg < 4; rg++) {
                int r = orow + mt * 16 + g4 * 4 + rg;
                #pragma unroll
                for (int np = 0; np < 2; np++) {
                    u32 t = __builtin_amdgcn_cvt_pk_fp8_f32(
                        acc[mt][np * 2][rg] + b[np * 2],
                        acc[mt][np * 2 + 1][rg] + b[np * 2 + 1], 0, false);
                    *(u16*)(out + (size_t)r * 768 + ocol + np * 32 + l15 * 2) = (u16)t;
                }
            }
    }
};
struct EpiMLP1 {   // sigmoid-gelu, pi64 u32-packed fp8
    const float* bias; u8* h;
    __device__ void store(int orow, int ocol, int l15, int g4, const f32x4 (&acc)[4][4]) const {
        float b[4];
        #pragma unroll
        for (int nt = 0; nt < 4; nt++) b[nt] = bias[ocol + nt * 16 + l15];
        #pragma unroll
        for (int mt = 0; mt < 4; mt++)
            #pragma unroll
            for (int rg = 0; rg < 4; rg++) {
                int r = orow + mt * 16 + g4 * 4 + rg;
                float g0 = gelu_s(acc[mt][0][rg] + b[0]);
                float g1 = gelu_s(acc[mt][1][rg] + b[1]);
                float g2 = gelu_s(acc[mt][2][rg] + b[2]);
                float g3 = gelu_s(acc[mt][3][rg] + b[3]);
                u32 v = __builtin_amdgcn_cvt_pk_fp8_f32(g0, g1, 0, false);
                v = (u32)__builtin_amdgcn_cvt_pk_fp8_f32(g2, g3, (int)v, true);
                *(u32*)(h + (size_t)r * 1024 + ocol + l15 * 4) = v;
            }
    }
};
struct EpiProj {   // bf16 XA out (logical layout)
    const float* bias; const float* ls1; const u16* Abuf; u16* xa;
    __device__ void store(int orow, int ocol, int l15, int g4, const f32x4 (&acc)[4][4]) const {
        float pb[4], l1[4];
        #pragma unroll
        for (int nt = 0; nt < 4; nt++) {
            int c = ocol + nt * 16 + l15;
            pb[nt] = bias[c]; l1[nt] = ls1[c];
        }
        #pragma unroll
        for (int mt = 0; mt < 4; mt++)
            #pragma unroll
            for (int rg = 0; rg < 4; rg++) {
                int r = orow + mt * 16 + g4 * 4 + rg;
                #pragma unroll
                for (int nt = 0; nt < 4; nt++) {
                    int c = ocol + nt * 16 + l15;
                    float val = bf2f(Abuf[(size_t)r * 256 + c]) + (acc[mt][nt][rg] + pb[nt]) * l1[nt];
                    xa[(size_t)r * 256 + c] = f2bf(val);
                }
            }
    }
};
struct EpiMLP2 {   // fp32 scatter to output
    const float* bias; const float* ls2; const u16* xa;
    const int* asy; const int* iwin; float* out;
    __device__ void store(int orow, int ocol, int l15, int g4, const f32x4 (&acc)[4][4]) const {
        float b[4], l2[4];
        #pragma unroll
        for (int nt = 0; nt < 4; nt++) {
            int c = ocol + nt * 16 + l15;
            b[nt] = bias[c]; l2[nt] = ls2[c];
        }
        #pragma unroll
        for (int mt = 0; mt < 4; mt++)
            #pragma unroll
            for (int rg = 0; rg < 4; rg++) {
                int r = orow + mt * 16 + g4 * 4 + rg;
                int flat = asy[r];
                size_t ob = ((size_t)iwin[flat >> 6] * P + (flat & 63)) * C;
                #pragma unroll
                for (int nt = 0; nt < 4; nt++) {
                    int c = ocol + nt * 16 + l15;
                    out[ob + c] = bf2f(xa[(size_t)r * 256 + c]) + (acc[mt][nt][rg] + b[nt]) * l2[nt];
                }
            }
    }
};

// ---------- fused per-window attention (fp8; position-based reads, packed writes) ----------
__global__ __launch_bounds__(256) void attn_kernel(const u8* __restrict__ QKV,
                                                   u8* __restrict__ out) {
    __shared__ u8 lds[4 * (48 * 80 + 32 * 80)];
    int m = blockIdx.x;
    int t = threadIdx.x, l = t & 63, w = t >> 6;
    int l15 = l & 15, g4 = l >> 4;
    u8* Pb = lds + w * (48 * 80 + 32 * 80);
    u8* Vt = Pb + 48 * 80;

    u32* z = (u32*)Pb;
    for (int i = l; i < (48 * 80 + 32 * 80) / 4; i += 64) z[i] = 0;

    const float scale = 0.17677669529663687f; // 32^-0.5

    for (int hh = 0; hh < 2; hh++) {
        int h = w + hh * 4;
        const u8* base = QKV + (size_t)m * REAL * 768 + h * 96;

        for (int i = l; i < REAL * 8; i += 64) {
            int kk = i >> 3, dg = i & 7;
            u32 vv = *(const u32*)(base + (size_t)kk * 768 + 64 + dg * 4);
            #pragma unroll
            for (int j = 0; j < 4; j++) Vt[(dg * 4 + j) * 80 + kk] = (u8)(vv >> (j * 8));
        }

        long qf[3], kf[3];
        #pragma unroll
        for (int mt = 0; mt < 3; mt++) {
            int q = mt * 16 + l15;
            qf[mt] = (q < REAL) ? *(const long*)(base + (size_t)q * 768 + g4 * 8) : 0L;
        }
        #pragma unroll
        for (int nt = 0; nt < 3; nt++) {
            int kk = nt * 16 + l15;
            kf[nt] = (kk < REAL) ? *(const long*)(base + (size_t)kk * 768 + 32 + g4 * 8) : 0L;
        }
        f32x4 s[3][3];
        #pragma unroll
        for (int a = 0; a < 3; a++)
            #pragma unroll
            for (int bb = 0; bb < 3; bb++)
                #pragma unroll
                for (int i = 0; i < 4; i++) s[a][bb][i] = 0.0f;
        #pragma unroll
        for (int mt = 0; mt < 3; mt++)
            #pragma unroll
            for (int nt = 0; nt < 3; nt++)
                s[mt][nt] = __builtin_amdgcn_mfma_f32_16x16x32_fp8_fp8(qf[mt], kf[nt], s[mt][nt], 0, 0, 0);

        #pragma unroll
        for (int mt = 0; mt < 3; mt++) {
            #pragma unroll
            for (int rg = 0; rg < 4; rg++) {
                float v0 = s[mt][0][rg] * scale;
                float v1 = s[mt][1][rg] * scale;
                float v2 = s[mt][2][rg] * scale;
                bool k2ok = (32 + l15) < REAL;
                float mx = fmaxf(fmaxf(v0, v1), k2ok ? v2 : -1e30f);
                #pragma unroll
                for (int xm = 1; xm < 16; xm <<= 1) mx = fmaxf(mx, __shfl_xor(mx, xm));
                float e0 = __expf(v0 - mx);
                float e1 = __expf(v1 - mx);
                float e2 = k2ok ? __expf(v2 - mx) : 0.0f;
                float sm = e0 + e1 + e2;
                #pragma unroll
                for (int xm = 1; xm < 16; xm <<= 1) sm += __shfl_xor(sm, xm);
                float inv = 1.0f / sm;
                int q = mt * 16 + g4 * 4 + rg;
                Pb[q * 80 + l15]      = f2fp8(e0 * inv);
                Pb[q * 80 + 16 + l15] = f2fp8(e1 * inv);
                Pb[q * 80 + 32 + l15] = k2ok ? f2fp8(e2 * inv) : (u8)0;
            }
        }

        f32x4 o[3][2];
        #pragma unroll
        for (int a = 0; a < 3; a++)
            #pragma unroll
            for (int bb = 0; bb < 2; bb++)
                #pragma unroll
                for (int i = 0; i < 4; i++) o[a][bb][i] = 0.0f;
        #pragma unroll
        for (int kt = 0; kt < 2; kt++) {
            long pf[3], vf[2];
            #pragma unroll
            for (int mt = 0; mt < 3; mt++)
                pf[mt] = *(const long*)(Pb + (mt * 16 + l15) * 80 + kt * 32 + g4 * 8);
            #pragma unroll
            for (int nt = 0; nt < 2; nt++)
                vf[nt] = *(const long*)(Vt + (nt * 16 + l15) * 80 + kt * 32 + g4 * 8);
            #pragma unroll
            for (int mt = 0; mt < 3; mt++)
                #pragma unroll
                for (int nt = 0; nt < 2; nt++)
                    o[mt][nt] = __builtin_amdgcn_mfma_f32_16x16x32_fp8_fp8(pf[mt], vf[nt], o[mt][nt], 0, 0, 0);
        }
        // packed u16 stores; stored pos = pi32(n) within the head's 32-byte group
        #pragma unroll
        for (int mt = 0; mt < 3; mt++)
            #pragma unroll
            for (int rg = 0; rg < 4; rg++) {
                int q = mt * 16 + g4 * 4 + rg;
                if (q < REAL) {
                    u32 tt = __builtin_amdgcn_cvt_pk_fp8_f32(o[mt][0][rg], o[mt][1][rg], 0, false);
                    *(u16*)(out + ((size_t)m * REAL + q) * 256 + h * 32 + l15 * 2) = (u16)tt;
                }
            }
    }
}

extern "C" void kernel_launch(void* const* d_in, const int* in_sizes, int n_in,
                              void* d_out, int out_size, void* d_ws, size_t ws_size,
                              hipStream_t stream) {
    const float* x      = (const float*)d_in[0];
    const float* qkv_w  = (const float*)d_in[1];
    const float* qkv_b  = (const float*)d_in[2];
    const float* proj_w = (const float*)d_in[3];
    const float* proj_b = (const float*)d_in[4];
    const float* n1g    = (const float*)d_in[5];
    const float* n1b    = (const float*)d_in[6];
    const float* n2g    = (const float*)d_in[7];
    const float* n2b    = (const float*)d_in[8];
    const float* ls1    = (const float*)d_in[9];
    const float* ls2    = (const float*)d_in[10];
    const float* w1     = (const float*)d_in[11];
    const float* b1     = (const float*)d_in[12];
    const float* w2     = (const float*)d_in[13];
    const float* b2     = (const float*)d_in[14];
    const int*   iwin   = (const int*)d_in[15];
    const int*   asy    = (const int*)d_in[18];
    float* out = (float*)d_out;
    u8* ws = (u8*)d_ws;

    u16* WqkvT  = (u16*)(ws + B_WQKVT);
    u16* W1T    = (u16*)(ws + B_W1T);
    u8*  ProjT8 = ws + B_PROJT8;
    u8*  W2T8   = ws + B_W2T8;
    int* inv    = (int*)(ws + B_INV);
    u16* Abuf   = (u16*)(ws + B_ABUF);
    u16* XA     = (u16*)(ws + B_XA);
    u8*  QKV8   = ws + B_QKV8;
    u8*  AttnO8 = ws + B_ATTNO8;
    u8*  H8     = ws + B_H8;          // aliases QKV8+AttnO8 (dead by MLP1)

    prep_weights<<<3584, 256, 0, stream>>>(qkv_w, proj_w, w1, w2, ws);
    build_inv<<<240, 256, 0, stream>>>(asy, iwin, inv);
    ln12_kernel<<<(NWIN * P) / 4, 256, 0, stream>>>(x, n1g, n1b, n2g, n2b, inv, out, Abuf);
    {
        int nwg = (MROWS / 128) * 6;
        gemm_bt<768, 256, EpiQKV8><<<nwg, 256, 0, stream>>>(Abuf, WqkvT, EpiQKV8{qkv_b, QKV8}, nwg / 8);
    }
    attn_kernel<<<MSEL, 256, 0, stream>>>(QKV8, AttnO8);
    {
        int nwg = (MROWS / 128) * 2;
        gemm_bt8<256, 256, EpiProj><<<nwg, 256, 0, stream>>>(AttnO8, ProjT8, EpiProj{proj_b, ls1, Abuf, XA}, nwg / 8);
    }
    {
        int nwg = (MROWS / 128) * 8;
        gemm_bt<1024, 256, EpiMLP1><<<nwg, 256, 0, stream>>>(XA, W1T, EpiMLP1{b1, H8}, nwg / 8);
    }
    {
        int nwg = (MROWS / 128) * 2;
        gemm_bt8<256, 1024, EpiMLP2><<<nwg, 256, 0, stream>>>(H8, W2T8, EpiMLP2{b2, ls2, XA, asy, iwin, out}, nwg / 8);
    }
}